// Round 1
// baseline (428.246 us; speedup 1.0000x reference)
//
#include <hip/hip_runtime.h>
#include <math.h>

#define NIMG 8
#define NCLS 80
#define HH 200
#define WW 200
#define HW (HH*WW)          // 40000
#define M (NCLS*HW)         // 3,200,000 entries per image
#define NBINS 8192
#define BIN_SHIFT 18        // top 14 bits of positive float
#define CAND_MAX 6144
#define TOPK 1000
#define OUTK 100
#define PRE_T 0.05f
#define NMS_T 0.6f

// scratch in device globals: no ws_size dependence, zeroed each launch by k0
__device__ unsigned int       g_hist[NIMG][NBINS];
__device__ unsigned int       g_cnt[NIMG];
__device__ unsigned int       g_cut[NIMG];
__device__ unsigned long long g_cand[NIMG][CAND_MAX];
__device__ unsigned long long g_top[NIMG][1024];

__device__ __forceinline__ float sigmoidf_(float x){
    return 1.0f / (1.0f + expf(-x));
}

__global__ void k0_zero(){
    int t = blockIdx.x * blockDim.x + threadIdx.x;
    int total = NIMG * NBINS;
    for (int i = t; i < total; i += gridDim.x * blockDim.x)
        ((unsigned int*)g_hist)[i] = 0u;
    if (t < NIMG){ g_cnt[t] = 0u; g_cut[t] = 0u; }
}

// Pass 1: per-image 8192-bin histogram of score bits (LDS-accumulated)
__global__ void k1_hist(const float* __restrict__ cls, const float* __restrict__ cent){
    int n = blockIdx.y;
    __shared__ unsigned int sh[NBINS];
    for (int i = threadIdx.x; i < NBINS; i += blockDim.x) sh[i] = 0u;
    __syncthreads();
    const int chunk = (M + gridDim.x - 1) / gridDim.x;
    int beg = blockIdx.x * chunk;
    int end = min(M, beg + chunk);
    const float* cls_n  = cls  + (size_t)n * M;
    const float* cent_n = cent + (size_t)n * HW;
    for (int t = beg + threadIdx.x; t < end; t += blockDim.x){
        float p = sigmoidf_(cls_n[t]);          // t = c*HW + hw
        if (p > PRE_T){
            int hw = t % HW;
            float s = p * sigmoidf_(cent_n[hw]);
            unsigned int bits = __float_as_uint(s);  // s>0 -> monotonic bits
            atomicAdd(&sh[bits >> BIN_SHIFT], 1u);
        }
    }
    __syncthreads();
    for (int i = threadIdx.x; i < NBINS; i += blockDim.x){
        unsigned int v = sh[i];
        if (v) atomicAdd(&g_hist[n][i], v);
    }
}

// Pass 2: find cut bin: smallest bin with suffix count >= TOPK (capped at CAND_MAX)
__global__ void k2_cut(){
    int n = blockIdx.x;
    __shared__ unsigned int csum[256];
    unsigned int s = 0;
    int base = threadIdx.x * 32;
    for (int i = 0; i < 32; ++i) s += g_hist[n][base + i];
    csum[threadIdx.x] = s;
    __syncthreads();
    if (threadIdx.x == 0){
        unsigned int acc = 0;
        int cut = 0;
        int c;
        for (c = 255; c >= 0; --c){
            if (acc + csum[c] >= TOPK) break;
            acc += csum[c];
        }
        if (c >= 0){
            int b;
            for (b = c*32 + 31; b >= c*32; --b){
                acc += g_hist[n][b];
                if (acc >= TOPK) break;
            }
            cut = b;
        }
        // acc = suffix count at cut (or grand total if < TOPK candidates exist)
        unsigned int cnt = acc;
        while (cnt > CAND_MAX && cut < NBINS){ cnt -= g_hist[n][cut]; cut++; }
        g_cut[n] = (unsigned int)cut;
    }
}

// Pass 3: collect candidates with bin >= cut as 64-bit keys
__global__ void k3_collect(const float* __restrict__ cls, const float* __restrict__ cent){
    int n = blockIdx.y;
    unsigned int cut = g_cut[n];
    const int chunk = (M + gridDim.x - 1) / gridDim.x;
    int beg = blockIdx.x * chunk;
    int end = min(M, beg + chunk);
    const float* cls_n  = cls  + (size_t)n * M;
    const float* cent_n = cent + (size_t)n * HW;
    for (int t = beg + threadIdx.x; t < end; t += blockDim.x){
        float p = sigmoidf_(cls_n[t]);
        if (p > PRE_T){
            int hw = t % HW;
            int c  = t / HW;
            float s = p * sigmoidf_(cent_n[hw]);
            unsigned int bits = __float_as_uint(s);
            if ((bits >> BIN_SHIFT) >= cut){
                unsigned int pos = atomicAdd(&g_cnt[n], 1u);
                if (pos < CAND_MAX){
                    unsigned int idx = (unsigned int)(hw * NCLS + c);  // ref flat index
                    // desc score, asc index on ties (matches jax top_k)
                    g_cand[n][pos] = ((unsigned long long)bits << 32)
                                   | (unsigned long long)(0xFFFFFFFFu - idx);
                }
            }
        }
    }
}

// Pass 4: exact rank-based top-1000 (keys unique -> ranks unique)
__global__ void __launch_bounds__(1024) k4_select(){
    int n = blockIdx.x;
    __shared__ unsigned long long keys[CAND_MAX];
    unsigned int cc = g_cnt[n];
    int C = (int)(cc < (unsigned int)CAND_MAX ? cc : (unsigned int)CAND_MAX);
    for (int i = threadIdx.x; i < C; i += blockDim.x) keys[i] = g_cand[n][i];
    g_top[n][threadIdx.x] = 0ull;   // blockDim == 1024 covers the array
    __syncthreads();
    for (int i = threadIdx.x; i < C; i += blockDim.x){
        unsigned long long k = keys[i];
        int rank = 0;
        for (int j = 0; j < C; ++j) rank += (keys[j] > k) ? 1 : 0;
        if (rank < TOPK) g_top[n][rank] = k;
    }
}

// Pass 5: decode boxes, greedy NMS with early stop at 100 keeps, write output
__global__ void __launch_bounds__(1024) k5_nms(const float* __restrict__ loc,
                                               const float* __restrict__ reg,
                                               const int*   __restrict__ imsz,
                                               float* __restrict__ out){
    int n = blockIdx.x;
    int t = threadIdx.x;
    __shared__ float ox1[TOPK], oy1[TOPK], ox2[TOPK], oy2[TOPK], oar[TOPK];
    __shared__ float bx[TOPK][4];
    __shared__ float sc[TOPK];
    __shared__ int   lab[TOPK];
    __shared__ unsigned char validf[TOPK];
    __shared__ unsigned char supp[TOPK];
    __shared__ int keeplist[OUTK];

    if (t < TOPK){
        unsigned long long k = g_top[n][t];
        unsigned int bits = (unsigned int)(k >> 32);
        float s = __uint_as_float(bits);
        supp[t] = 0;
        if (s > 0.0f){
            unsigned int idx = 0xFFFFFFFFu - (unsigned int)(k & 0xFFFFFFFFull);
            int hw = (int)(idx / NCLS);
            int c  = (int)(idx % NCLS);
            int l  = c + 1;
            float x  = loc[2*hw], y = loc[2*hw + 1];
            float r0 = reg[((size_t)n*4 + 0)*HW + hw];
            float r1 = reg[((size_t)n*4 + 1)*HW + hw];
            float r2 = reg[((size_t)n*4 + 2)*HW + hw];
            float r3 = reg[((size_t)n*4 + 3)*HW + hw];
            float ihh = (float)imsz[2*n + 0];
            float iww = (float)imsz[2*n + 1];
            float x1 = fminf(fmaxf(x - r0, 0.0f), iww - 1.0f);
            float y1 = fminf(fmaxf(y - r1, 0.0f), ihh - 1.0f);
            float x2 = fminf(fmaxf(x + r2, 0.0f), iww - 1.0f);
            float y2 = fminf(fmaxf(y + r3, 0.0f), ihh - 1.0f);
            bx[t][0] = x1; bx[t][1] = y1; bx[t][2] = x2; bx[t][3] = y2;
            float off = (float)l * 100000.0f;   // fp32, as reference (quantizes!)
            float a1 = x1 + off, b1 = y1 + off, a2 = x2 + off, b2 = y2 + off;
            ox1[t] = a1; oy1[t] = b1; ox2[t] = a2; oy2[t] = b2;
            oar[t] = (a2 - a1 + 1.0f) * (b2 - b1 + 1.0f);
            sc[t] = s; lab[t] = l; validf[t] = 1;
        } else {
            validf[t] = 0; sc[t] = 0.0f; lab[t] = 0;
            bx[t][0] = bx[t][1] = bx[t][2] = bx[t][3] = 0.0f;
            ox1[t] = oy1[t] = 0.0f; ox2[t] = oy2[t] = -1.0f; oar[t] = 1.0f;
        }
    }
    __syncthreads();

    int cnt = 0;   // replicated uniformly in every thread
    for (int i = 0; i < TOPK; ++i){
        bool keep_i = validf[i] && !supp[i];   // uniform LDS broadcast read
        if (keep_i){
            if (t == 0) keeplist[cnt] = i;
            if (t < TOPK && t != i){
                float ix1 = fmaxf(ox1[i], ox1[t]);
                float iy1 = fmaxf(oy1[i], oy1[t]);
                float ix2 = fminf(ox2[i], ox2[t]);
                float iy2 = fminf(oy2[i], oy2[t]);
                float iw_ = fmaxf(ix2 - ix1 + 1.0f, 0.0f);
                float ih_ = fmaxf(iy2 - iy1 + 1.0f, 0.0f);
                float inter = iw_ * ih_;
                float iou = inter / (oar[i] + oar[t] - inter);
                if (iou > NMS_T) supp[t] = 1;
            }
            cnt++;
            __syncthreads();              // uniform: keep_i same for all threads
            if (cnt == OUTK) break;       // keeps beyond 100 can't reach output
        }
    }
    __syncthreads();

    if (t < OUTK){
        float r0=0.f,r1=0.f,r2=0.f,r3=0.f,r4=0.f,r5=0.f;
        if (t < cnt){
            int i = keeplist[t];
            r0 = bx[i][0]; r1 = bx[i][1]; r2 = bx[i][2]; r3 = bx[i][3];
            r4 = sqrtf(sc[i]); r5 = (float)lab[i];
        }
        float* o = out + ((size_t)n*OUTK + t)*6;
        o[0]=r0; o[1]=r1; o[2]=r2; o[3]=r3; o[4]=r4; o[5]=r5;
    }
}

extern "C" void kernel_launch(void* const* d_in, const int* in_sizes, int n_in,
                              void* d_out, int out_size, void* d_ws, size_t ws_size,
                              hipStream_t stream){
    const float* loc  = (const float*)d_in[0];
    const float* cls  = (const float*)d_in[1];
    const float* reg  = (const float*)d_in[2];
    const float* cent = (const float*)d_in[3];
    const int*   imsz = (const int*)d_in[4];
    float* out = (float*)d_out;

    hipLaunchKernelGGL(k0_zero,    dim3(64),        dim3(256),  0, stream);
    hipLaunchKernelGGL(k1_hist,    dim3(256, NIMG), dim3(256),  0, stream, cls, cent);
    hipLaunchKernelGGL(k2_cut,     dim3(NIMG),      dim3(256),  0, stream);
    hipLaunchKernelGGL(k3_collect, dim3(256, NIMG), dim3(256),  0, stream, cls, cent);
    hipLaunchKernelGGL(k4_select,  dim3(NIMG),      dim3(1024), 0, stream);
    hipLaunchKernelGGL(k5_nms,     dim3(NIMG),      dim3(1024), 0, stream,
                       loc, reg, imsz, out);
}

// Round 2
// 349.282 us; speedup vs baseline: 1.2261x; 1.2261x over previous
//
#include <hip/hip_runtime.h>
#include <math.h>

#define NIMG 8
#define NCLS 80
#define HH 200
#define WW 200
#define HW (HH*WW)          // 40000
#define M (NCLS*HW)         // 3,200,000 entries per image
#define NBINS 8192
#define BIN_SHIFT 18        // top 14 bits of positive float (1 sign+8 exp+5 mant)
#define CAND_MAX 6144
#define TOPK 1000
#define OUTK 100
#define PRE_T 0.05f
#define PRE_T_LOOSE 0.0499f
#define NMS_T 0.6f
#define L2E 1.44269504f

// scratch in device globals: no ws_size dependence, re-inited each launch by k0
__device__ unsigned int       g_hist[NIMG][NBINS];
__device__ unsigned int       g_cnt[NIMG];
__device__ unsigned int       g_cut[NIMG];
__device__ float              g_sct[NIMG * HW];     // exact sigmoid(centerness)
__device__ unsigned long long g_cand[NIMG][CAND_MAX];
__device__ unsigned long long g_top[NIMG][1024];

__device__ __forceinline__ float sigmoid_exact(float x){
    return 1.0f / (1.0f + expf(-x));      // bit-matches JAX on this data (r1: absmax 0)
}
__device__ __forceinline__ float sigmoid_fast(float x){
    // 2-3 ulp approx: v_exp_f32 + v_rcp_f32. Used ONLY for screening/binning.
    return __builtin_amdgcn_rcpf(1.0f + __builtin_amdgcn_exp2f(-x * L2E));
}

// init: zero hist/counters + exact sigmoid(centerness) table
__global__ void k0_init(const float* __restrict__ cent){
    int t = blockIdx.x * blockDim.x + threadIdx.x;
    int stride = gridDim.x * blockDim.x;
    for (int i = t; i < NIMG * NBINS; i += stride)
        ((unsigned int*)g_hist)[i] = 0u;
    if (t < NIMG){ g_cnt[t] = 0u; g_cut[t] = 0u; }
    for (int i = t; i < NIMG * HW; i += stride)
        g_sct[i] = sigmoid_exact(cent[i]);
}

// Pass 1: per-image 8192-bin histogram of APPROX score bits
__global__ void __launch_bounds__(1024) k1_hist(const float* __restrict__ cls){
    int n = blockIdx.y;
    __shared__ unsigned int sh[NBINS];
    for (int i = threadIdx.x; i < NBINS; i += 1024) sh[i] = 0u;
    __syncthreads();
    const int chunk = M / 32;                 // 100000, multiple of 4
    int beg = blockIdx.x * chunk;
    const float4* cls4  = (const float4*)(cls + (size_t)n * M + beg);
    const float*  sct_n = g_sct + n * HW;
    const int n4 = chunk / 4;                 // 25000
    for (int i = threadIdx.x; i < n4; i += 1024){
        float4 x = cls4[i];
        int t0 = beg + i * 4;
        int hw = t0 % HW;                     // all 4 share one spatial row
        float4 ct = *(const float4*)(sct_n + hw);
        float pa0 = sigmoid_fast(x.x), pa1 = sigmoid_fast(x.y);
        float pa2 = sigmoid_fast(x.z), pa3 = sigmoid_fast(x.w);
        if (pa0 > PRE_T_LOOSE) atomicAdd(&sh[__float_as_uint(pa0 * ct.x) >> BIN_SHIFT], 1u);
        if (pa1 > PRE_T_LOOSE) atomicAdd(&sh[__float_as_uint(pa1 * ct.y) >> BIN_SHIFT], 1u);
        if (pa2 > PRE_T_LOOSE) atomicAdd(&sh[__float_as_uint(pa2 * ct.z) >> BIN_SHIFT], 1u);
        if (pa3 > PRE_T_LOOSE) atomicAdd(&sh[__float_as_uint(pa3 * ct.w) >> BIN_SHIFT], 1u);
    }
    __syncthreads();
    for (int i = threadIdx.x; i < NBINS; i += 1024){
        unsigned int v = sh[i];
        if (v) atomicAdd(&g_hist[n][i], v);
    }
}

// Pass 2: cut = smallest bin with suffix >= TOPK, minus 1 bin of margin
// (absorbs approx-vs-exact rounding), clamped so suffix(cut) <= CAND_MAX.
__global__ void k2_cut(){
    int n = blockIdx.x;
    __shared__ unsigned int csum[256];
    unsigned int s = 0;
    int base = threadIdx.x * 32;
    for (int i = 0; i < 32; ++i) s += g_hist[n][base + i];
    csum[threadIdx.x] = s;
    __syncthreads();
    if (threadIdx.x == 0){
        unsigned int acc = 0;
        int cut = 0;
        int c = 255;
        for (; c >= 0; --c){
            if (acc + csum[c] >= TOPK) break;
            acc += csum[c];
        }
        if (c >= 0){
            int b = c * 32 + 31;
            for (;; --b){
                acc += g_hist[n][b];
                if (acc >= TOPK || b == c * 32) break;
            }
            cut = b;
        }
        unsigned int cnt = acc;
        if (cut > 0){ cnt += g_hist[n][cut - 1]; cut--; }   // 1-bin margin
        while (cnt > CAND_MAX && cut < NBINS){ cnt -= g_hist[n][cut]; cut++; }
        g_cut[n] = (unsigned int)cut;
    }
}

// Pass 3: approx-screen, then EXACT score bits (same formula as reference) for keys
__global__ void k3_collect(const float* __restrict__ cls){
    int n = blockIdx.y;
    unsigned int cut = g_cut[n];
    const int chunk = M / 256;                // 12500, multiple of 4
    int beg = blockIdx.x * chunk;
    const float*  cls_n = cls + (size_t)n * M;
    const float4* cls4  = (const float4*)(cls_n + beg);
    const float*  sct_n = g_sct + n * HW;
    const int n4 = chunk / 4;                 // 3125
    for (int i = threadIdx.x; i < n4; i += blockDim.x){
        float4 x = cls4[i];
        int t0 = beg + i * 4;
        int hw0 = t0 % HW;
        float4 ct = *(const float4*)(sct_n + hw0);
        float xs[4] = {x.x, x.y, x.z, x.w};
        float cs[4] = {ct.x, ct.y, ct.z, ct.w};
        #pragma unroll
        for (int k = 0; k < 4; ++k){
            float pa = sigmoid_fast(xs[k]);
            if (pa > PRE_T_LOOSE){
                float sa = pa * cs[k];
                if ((__float_as_uint(sa) >> BIN_SHIFT) >= cut){
                    float p = sigmoid_exact(xs[k]);
                    if (p > PRE_T){
                        float sx = p * cs[k];                 // exact ref score
                        unsigned int bits = __float_as_uint(sx);
                        unsigned int pos = atomicAdd(&g_cnt[n], 1u);
                        if (pos < CAND_MAX){
                            int t = t0 + k;
                            int hw = hw0 + k;
                            int c  = t / HW;
                            unsigned int idx = (unsigned int)(hw * NCLS + c);
                            g_cand[n][pos] = ((unsigned long long)bits << 32)
                                           | (unsigned long long)(0xFFFFFFFFu - idx);
                        }
                    }
                }
            }
        }
    }
}

// Pass 4: exact rank-based top-1000 (keys unique -> ranks unique)
__global__ void __launch_bounds__(1024) k4_select(){
    int n = blockIdx.x;
    __shared__ unsigned long long keys[CAND_MAX];
    unsigned int cc = g_cnt[n];
    int C = (int)(cc < (unsigned int)CAND_MAX ? cc : (unsigned int)CAND_MAX);
    for (int i = threadIdx.x; i < C; i += blockDim.x) keys[i] = g_cand[n][i];
    g_top[n][threadIdx.x] = 0ull;   // blockDim == 1024 covers the array
    __syncthreads();
    for (int i = threadIdx.x; i < C; i += blockDim.x){
        unsigned long long k = keys[i];
        int rank = 0;
        for (int j = 0; j < C; ++j) rank += (keys[j] > k) ? 1 : 0;
        if (rank < TOPK) g_top[n][rank] = k;
    }
}

// Pass 5: decode boxes, greedy NMS with early stop at 100 keeps, write output
__global__ void __launch_bounds__(1024) k5_nms(const float* __restrict__ loc,
                                               const float* __restrict__ reg,
                                               const int*   __restrict__ imsz,
                                               float* __restrict__ out){
    int n = blockIdx.x;
    int t = threadIdx.x;
    __shared__ float ox1[TOPK], oy1[TOPK], ox2[TOPK], oy2[TOPK], oar[TOPK];
    __shared__ float bx[TOPK][4];
    __shared__ float sc[TOPK];
    __shared__ int   lab[TOPK];
    __shared__ unsigned char validf[TOPK];
    __shared__ unsigned char supp[TOPK];
    __shared__ int keeplist[OUTK];

    if (t < TOPK){
        unsigned long long k = g_top[n][t];
        unsigned int bits = (unsigned int)(k >> 32);
        float s = __uint_as_float(bits);
        supp[t] = 0;
        if (s > 0.0f){
            unsigned int idx = 0xFFFFFFFFu - (unsigned int)(k & 0xFFFFFFFFull);
            int hw = (int)(idx / NCLS);
            int c  = (int)(idx % NCLS);
            int l  = c + 1;
            float x  = loc[2*hw], y = loc[2*hw + 1];
            float r0 = reg[((size_t)n*4 + 0)*HW + hw];
            float r1 = reg[((size_t)n*4 + 1)*HW + hw];
            float r2 = reg[((size_t)n*4 + 2)*HW + hw];
            float r3 = reg[((size_t)n*4 + 3)*HW + hw];
            float ihh = (float)imsz[2*n + 0];
            float iww = (float)imsz[2*n + 1];
            float x1 = fminf(fmaxf(x - r0, 0.0f), iww - 1.0f);
            float y1 = fminf(fmaxf(y - r1, 0.0f), ihh - 1.0f);
            float x2 = fminf(fmaxf(x + r2, 0.0f), iww - 1.0f);
            float y2 = fminf(fmaxf(y + r3, 0.0f), ihh - 1.0f);
            bx[t][0] = x1; bx[t][1] = y1; bx[t][2] = x2; bx[t][3] = y2;
            float off = (float)l * 100000.0f;   // fp32, as reference (quantizes!)
            float a1 = x1 + off, b1 = y1 + off, a2 = x2 + off, b2 = y2 + off;
            ox1[t] = a1; oy1[t] = b1; ox2[t] = a2; oy2[t] = b2;
            oar[t] = (a2 - a1 + 1.0f) * (b2 - b1 + 1.0f);
            sc[t] = s; lab[t] = l; validf[t] = 1;
        } else {
            validf[t] = 0; sc[t] = 0.0f; lab[t] = 0;
            bx[t][0] = bx[t][1] = bx[t][2] = bx[t][3] = 0.0f;
            ox1[t] = oy1[t] = 0.0f; ox2[t] = oy2[t] = -1.0f; oar[t] = 1.0f;
        }
    }
    __syncthreads();

    int cnt = 0;   // replicated uniformly in every thread
    for (int i = 0; i < TOPK; ++i){
        bool keep_i = validf[i] && !supp[i];   // uniform LDS broadcast read
        if (keep_i){
            if (t == 0) keeplist[cnt] = i;
            if (t < TOPK && t != i){
                float ix1 = fmaxf(ox1[i], ox1[t]);
                float iy1 = fmaxf(oy1[i], oy1[t]);
                float ix2 = fminf(ox2[i], ox2[t]);
                float iy2 = fminf(oy2[i], oy2[t]);
                float iw_ = fmaxf(ix2 - ix1 + 1.0f, 0.0f);
                float ih_ = fmaxf(iy2 - iy1 + 1.0f, 0.0f);
                float inter = iw_ * ih_;
                float iou = inter / (oar[i] + oar[t] - inter);
                if (iou > NMS_T) supp[t] = 1;
            }
            cnt++;
            __syncthreads();              // uniform: keep_i same for all threads
            if (cnt == OUTK) break;       // keeps beyond 100 can't reach output
        }
    }
    __syncthreads();

    if (t < OUTK){
        float r0=0.f,r1=0.f,r2=0.f,r3=0.f,r4=0.f,r5=0.f;
        if (t < cnt){
            int i = keeplist[t];
            r0 = bx[i][0]; r1 = bx[i][1]; r2 = bx[i][2]; r3 = bx[i][3];
            r4 = sqrtf(sc[i]); r5 = (float)lab[i];
        }
        float* o = out + ((size_t)n*OUTK + t)*6;
        o[0]=r0; o[1]=r1; o[2]=r2; o[3]=r3; o[4]=r4; o[5]=r5;
    }
}

extern "C" void kernel_launch(void* const* d_in, const int* in_sizes, int n_in,
                              void* d_out, int out_size, void* d_ws, size_t ws_size,
                              hipStream_t stream){
    const float* loc  = (const float*)d_in[0];
    const float* cls  = (const float*)d_in[1];
    const float* reg  = (const float*)d_in[2];
    const float* cent = (const float*)d_in[3];
    const int*   imsz = (const int*)d_in[4];
    float* out = (float*)d_out;

    hipLaunchKernelGGL(k0_init,    dim3(1250),     dim3(256),  0, stream, cent);
    hipLaunchKernelGGL(k1_hist,    dim3(32, NIMG), dim3(1024), 0, stream, cls);
    hipLaunchKernelGGL(k2_cut,     dim3(NIMG),     dim3(256),  0, stream);
    hipLaunchKernelGGL(k3_collect, dim3(256, NIMG),dim3(256),  0, stream, cls);
    hipLaunchKernelGGL(k4_select,  dim3(NIMG),     dim3(1024), 0, stream);
    hipLaunchKernelGGL(k5_nms,     dim3(NIMG),     dim3(1024), 0, stream,
                       loc, reg, imsz, out);
}